// Round 1
// baseline (88.930 us; speedup 1.0000x reference)
//
#include <hip/hip_runtime.h>
#include <stdint.h>

// Problem constants
#define DIM 256
#define NROWS 8192          // N == M == 8192
#define OUTC 8192

// GEMM tiling (m97 structure: 128x128 tile, BK=64, 4 waves, 16x16x32 bf16 MFMA)
#define BM 128
#define BN 128
#define BK 64

typedef __bf16 bf16x8_t __attribute__((ext_vector_type(8)));
typedef float f32x4_t __attribute__((ext_vector_type(4)));

__device__ __forceinline__ unsigned short f2bf_rne(float f) {
    unsigned int u = __float_as_uint(f);
    u += 0x7FFFu + ((u >> 16) & 1u);   // round-to-nearest-even
    return (unsigned short)(u >> 16);
}

// One wave per row: convert f32 row -> bf16, compute ||row||^2.
__global__ void prep_kernel(const float* __restrict__ src,
                            unsigned short* __restrict__ dst,
                            float* __restrict__ norms) {
    const int w = threadIdx.x >> 6;
    const int l = threadIdx.x & 63;
    const int row = blockIdx.x * 4 + w;
    const float4 v = reinterpret_cast<const float4*>(src + (size_t)row * DIM)[l];
    float ss = v.x * v.x + v.y * v.y + v.z * v.z + v.w * v.w;
#pragma unroll
    for (int off = 32; off > 0; off >>= 1) ss += __shfl_down(ss, off);
    if (l == 0) norms[row] = ss;
    ushort4 o = make_ushort4(f2bf_rne(v.x), f2bf_rne(v.y), f2bf_rne(v.z), f2bf_rne(v.w));
    reinterpret_cast<ushort4*>(dst + (size_t)row * DIM)[l] = o;
}

// C = A * B^T with fused hybrid-kernel epilogue.
// out[i][j] = 0.5*exp(-(na[i]+nb[j]-2*dot)) + 0.5*dot
__global__ __launch_bounds__(256) void gemm_kernel(
        const unsigned short* __restrict__ aB,
        const unsigned short* __restrict__ bB,
        const float* __restrict__ na,
        const float* __restrict__ nb,
        float* __restrict__ out) {
    __shared__ unsigned short sA[BM * BK];
    __shared__ unsigned short sB[BN * BK];

    const int t = threadIdx.x;
    const int w = t >> 6;          // wave 0..3
    const int l = t & 63;          // lane
    const int wr = w >> 1;         // wave row 0..1  (owns 64 rows)
    const int wc = w & 1;          // wave col 0..1  (owns 64 cols)

    const int by = blockIdx.x >> 6;    // 64 row tiles
    const int bx = blockIdx.x & 63;    // 64 col tiles
    const int row0 = by * BM;
    const int col0 = bx * BN;

    f32x4_t acc[4][4];
#pragma unroll
    for (int m = 0; m < 4; ++m)
#pragma unroll
        for (int n = 0; n < 4; ++n) acc[m][n] = (f32x4_t)0.0f;

    const int lr = l >> 3;          // row within 8-row staging group
    const int lc = (l & 7) * 8;     // bf16-element col within BK chunk
    const int fr = l & 15;          // fragment row/col index
    const int kq = l >> 4;          // k quarter 0..3

#pragma unroll
    for (int kt = 0; kt < DIM / BK; ++kt) {
        // ---- stage A,B tiles: global -> LDS, 16B per lane, linear layout ----
#pragma unroll
        for (int it = 0; it < 4; ++it) {
            const int rg = w * 4 + it;          // row-group 0..15 (8 rows each)
            const int r = rg * 8 + lr;          // 0..127
            const unsigned short* ga = aB + (size_t)(row0 + r) * DIM + kt * BK + lc;
            const unsigned short* gb = bB + (size_t)(col0 + r) * DIM + kt * BK + lc;
            __builtin_amdgcn_global_load_lds(
                (const __attribute__((address_space(1))) void*)ga,
                (__attribute__((address_space(3))) void*)&sA[rg * 8 * BK], 16, 0, 0);
            __builtin_amdgcn_global_load_lds(
                (const __attribute__((address_space(1))) void*)gb,
                (__attribute__((address_space(3))) void*)&sB[rg * 8 * BK], 16, 0, 0);
        }
        __syncthreads();

        // ---- compute: 2 k-subtiles of 32, 16 MFMA each ----
#pragma unroll
        for (int ks = 0; ks < 2; ++ks) {
            bf16x8_t af[4], bfr[4];
#pragma unroll
            for (int m = 0; m < 4; ++m)
                af[m] = *reinterpret_cast<const bf16x8_t*>(
                    &sA[(wr * 64 + m * 16 + fr) * BK + ks * 32 + kq * 8]);
#pragma unroll
            for (int n = 0; n < 4; ++n)
                bfr[n] = *reinterpret_cast<const bf16x8_t*>(
                    &sB[(wc * 64 + n * 16 + fr) * BK + ks * 32 + kq * 8]);
#pragma unroll
            for (int m = 0; m < 4; ++m)
#pragma unroll
                for (int n = 0; n < 4; ++n)
                    acc[m][n] = __builtin_amdgcn_mfma_f32_16x16x32_bf16(
                        af[m], bfr[n], acc[m][n], 0, 0, 0);
        }
        __syncthreads();
    }

    // ---- epilogue: out = 0.5*exp(-(na+nb-2c)) + 0.5*c ----
#pragma unroll
    for (int m = 0; m < 4; ++m) {
        const int rbase = row0 + wr * 64 + m * 16 + kq * 4;
#pragma unroll
        for (int q = 0; q < 4; ++q) {
            const int r = rbase + q;
            const float nar = na[r];
            const size_t ro = (size_t)r * OUTC;
#pragma unroll
            for (int n = 0; n < 4; ++n) {
                const int c = col0 + wc * 64 + n * 16 + fr;
                const float dot = acc[m][n][q];
                const float sq = nar + nb[c] - 2.0f * dot;
                out[ro + c] = 0.5f * __expf(-sq) + 0.5f * dot;
            }
        }
    }
}

// Fallback if workspace is too small: fully naive f32 (correct, slow).
__global__ void naive_kernel(const float* __restrict__ a,
                             const float* __restrict__ b,
                             float* __restrict__ out) {
    const size_t idx = (size_t)blockIdx.x * 256 + threadIdx.x;
    const int i = (int)(idx >> 13);
    const int j = (int)(idx & 8191);
    float dot = 0.f, naa = 0.f, nbb = 0.f;
    for (int k = 0; k < DIM; ++k) {
        const float x = a[(size_t)i * DIM + k];
        const float y = b[(size_t)j * DIM + k];
        dot += x * y; naa += x * x; nbb += y * y;
    }
    const float sq = naa + nbb - 2.0f * dot;
    out[idx] = 0.5f * __expf(-sq) + 0.5f * dot;
}

extern "C" void kernel_launch(void* const* d_in, const int* in_sizes, int n_in,
                              void* d_out, int out_size, void* d_ws, size_t ws_size,
                              hipStream_t stream) {
    const float* a = (const float*)d_in[0];
    const float* b = (const float*)d_in[1];
    // d_in[2] = Wq, d_in[3] = Wk: unused — softmax over a 1x1 score is exactly 1,
    // so attn_sim == a.b and the projections cancel out of the output.
    float* out = (float*)d_out;

    const size_t bf_bytes = (size_t)NROWS * DIM * sizeof(unsigned short); // 4 MB each
    const size_t nrm_bytes = (size_t)NROWS * sizeof(float);               // 32 KB each
    const size_t need = 2 * bf_bytes + 2 * nrm_bytes;

    if (ws_size >= need) {
        unsigned short* aBf = (unsigned short*)d_ws;
        unsigned short* bBf = (unsigned short*)((char*)d_ws + bf_bytes);
        float* na = (float*)((char*)d_ws + 2 * bf_bytes);
        float* nb = (float*)((char*)d_ws + 2 * bf_bytes + nrm_bytes);

        prep_kernel<<<NROWS / 4, 256, 0, stream>>>(a, aBf, na);
        prep_kernel<<<NROWS / 4, 256, 0, stream>>>(b, bBf, nb);
        gemm_kernel<<<(NROWS / BM) * (NROWS / BN), 256, 0, stream>>>(aBf, bBf, na, nb, out);
    } else {
        naive_kernel<<<((size_t)NROWS * NROWS) / 256, 256, 0, stream>>>(a, b, out);
    }
}

// Round 2
// 81.331 us; speedup vs baseline: 1.0934x; 1.0934x over previous
//
#include <hip/hip_runtime.h>
#include <stdint.h>

// Problem constants
#define DIM 256
#define NROWS 8192          // N == M == 8192
#define OUTC 8192

// GEMM tiling (m97 structure: 128x128 tile, BK=64, 4 waves, 16x16x32 bf16 MFMA)
#define BM 128
#define BN 128
#define BK 64
#define NTILES 4096         // (8192/128)^2
#define GRID_GEMM 2048      // 2 tiles per block, tile-boundary pipelined

typedef __bf16 bf16x8_t __attribute__((ext_vector_type(8)));
typedef float f32x4_t __attribute__((ext_vector_type(4)));

__device__ __forceinline__ unsigned short f2bf_rne(float f) {
    unsigned int u = __float_as_uint(f);
    u += 0x7FFFu + ((u >> 16) & 1u);   // round-to-nearest-even
    return (unsigned short)(u >> 16);
}

// One wave per row: convert f32 row -> bf16, compute ||row||^2.
// Single launch covers both tensors: blocks [0,2048) -> a, [2048,4096) -> b.
__global__ void prep_kernel(const float* __restrict__ a,
                            const float* __restrict__ b,
                            unsigned short* __restrict__ aB,
                            unsigned short* __restrict__ bB,
                            float* __restrict__ na,
                            float* __restrict__ nb) {
    const int w = threadIdx.x >> 6;
    const int l = threadIdx.x & 63;
    const int blk = blockIdx.x;
    const float* src;
    unsigned short* dst;
    float* nrm;
    int row;
    if (blk < 2048) { src = a; dst = aB; nrm = na; row = blk * 4 + w; }
    else            { src = b; dst = bB; nrm = nb; row = (blk - 2048) * 4 + w; }
    const float4 v = reinterpret_cast<const float4*>(src + (size_t)row * DIM)[l];
    float ss = v.x * v.x + v.y * v.y + v.z * v.z + v.w * v.w;
#pragma unroll
    for (int off = 32; off > 0; off >>= 1) ss += __shfl_down(ss, off);
    if (l == 0) nrm[row] = ss;
    ushort4 o = make_ushort4(f2bf_rne(v.x), f2bf_rne(v.y), f2bf_rne(v.z), f2bf_rne(v.w));
    reinterpret_cast<ushort4*>(dst + (size_t)row * DIM)[l] = o;
}

// Issue 8 global_load_lds (16B/lane, linear LDS) staging A,B K-tiles.
#define STAGE(row0_, col0_, kt_)                                                 \
    do {                                                                         \
        _Pragma("unroll")                                                        \
        for (int it = 0; it < 4; ++it) {                                         \
            const int rg_ = w * 4 + it;                                          \
            const int r_ = rg_ * 8 + lr;                                         \
            __builtin_amdgcn_global_load_lds(                                    \
                (const __attribute__((address_space(1))) void*)(aB +             \
                    (size_t)((row0_) + r_) * DIM + (kt_) * BK + lc),             \
                (__attribute__((address_space(3))) void*)&sA[rg_ * 8 * BK],      \
                16, 0, 0);                                                       \
            __builtin_amdgcn_global_load_lds(                                    \
                (const __attribute__((address_space(1))) void*)(bB +             \
                    (size_t)((col0_) + r_) * DIM + (kt_) * BK + lc),             \
                (__attribute__((address_space(3))) void*)&sB[rg_ * 8 * BK],      \
                16, 0, 0);                                                       \
        }                                                                        \
    } while (0)

// C = A * B^T with fused hybrid-kernel epilogue.
// out[i][j] = 0.5*exp(-(na[i]+nb[j]-2*dot)) + 0.5*dot
// 2 tiles per block; tile-1 staging is issued before tile-0's epilogue and the
// first barrier of tile 1 waits only vmcnt(56) so the 64 epilogue stores stay
// in flight (in-order vmcnt retire: >=36 oldest retired => 8 stage loads done).
__global__ __launch_bounds__(256) void gemm_kernel(
        const unsigned short* __restrict__ aB,
        const unsigned short* __restrict__ bB,
        const float* __restrict__ na,
        const float* __restrict__ nb,
        float* __restrict__ out) {
    __shared__ unsigned short sA[BM * BK];
    __shared__ unsigned short sB[BN * BK];

    const int t = threadIdx.x;
    const int w = t >> 6;          // wave 0..3
    const int l = t & 63;          // lane
    const int wr = w >> 1;         // wave row 0..1  (owns 64 rows)
    const int wc = w & 1;          // wave col 0..1  (owns 64 cols)

    const int lr = l >> 3;          // row within 8-row staging group
    const int lc = (l & 7) * 8;     // bf16-element col within BK chunk
    const int fr = l & 15;          // fragment row/col index
    const int kq = l >> 4;          // k quarter 0..3

    const int bid = blockIdx.x;

    // Prologue: stage first tile's kt=0.
    {
        const int row0 = (bid >> 6) * BM;
        const int col0 = (bid & 63) * BN;
        STAGE(row0, col0, 0);
    }

#pragma unroll
    for (int ti = 0; ti < 2; ++ti) {
        const int tile = bid + ti * GRID_GEMM;      // same bx both tiles (B panel L2-hot)
        const int row0 = (tile >> 6) * BM;
        const int col0 = (tile & 63) * BN;

        f32x4_t acc[4][4];
#pragma unroll
        for (int m = 0; m < 4; ++m)
#pragma unroll
            for (int n = 0; n < 4; ++n) acc[m][n] = (f32x4_t)0.0f;

#pragma unroll
        for (int kt = 0; kt < DIM / BK; ++kt) {
            if (kt == 0 && ti > 0) {
                // stage loads are the 8 oldest of >=72 outstanding vmem ops
                asm volatile("s_waitcnt vmcnt(56)" ::: "memory");
            } else {
                asm volatile("s_waitcnt vmcnt(0)" ::: "memory");
            }
            __builtin_amdgcn_s_barrier();
            asm volatile("" ::: "memory");

            // ---- compute: 2 k-subtiles of 32, 16 MFMA each ----
#pragma unroll
            for (int ks = 0; ks < 2; ++ks) {
                bf16x8_t af[4], bfr[4];
#pragma unroll
                for (int m = 0; m < 4; ++m)
                    af[m] = *reinterpret_cast<const bf16x8_t*>(
                        &sA[(wr * 64 + m * 16 + fr) * BK + ks * 32 + kq * 8]);
#pragma unroll
                for (int n = 0; n < 4; ++n)
                    bfr[n] = *reinterpret_cast<const bf16x8_t*>(
                        &sB[(wc * 64 + n * 16 + fr) * BK + ks * 32 + kq * 8]);
#pragma unroll
                for (int m = 0; m < 4; ++m)
#pragma unroll
                    for (int n = 0; n < 4; ++n)
                        acc[m][n] = __builtin_amdgcn_mfma_f32_16x16x32_bf16(
                            af[m], bfr[n], acc[m][n], 0, 0, 0);
            }

            asm volatile("" ::: "memory");
            __builtin_amdgcn_s_barrier();
            asm volatile("" ::: "memory");

            if (kt < DIM / BK - 1) {
                STAGE(row0, col0, kt + 1);
            } else if (ti == 0) {
                // stage next tile's kt=0 before this tile's epilogue
                const int nt_ = bid + GRID_GEMM;
                STAGE((nt_ >> 6) * BM, (nt_ & 63) * BN, 0);
            }
            asm volatile("" ::: "memory");
        }

        // ---- epilogue: out = 0.5*exp(-(na+nb-2c)) + 0.5*c (nontemporal) ----
#pragma unroll
        for (int m = 0; m < 4; ++m) {
            const int rbase = row0 + wr * 64 + m * 16 + kq * 4;
#pragma unroll
            for (int q = 0; q < 4; ++q) {
                const int r = rbase + q;
                const float nar = na[r];
                const size_t ro = (size_t)r * OUTC;
#pragma unroll
                for (int n = 0; n < 4; ++n) {
                    const int c = col0 + wc * 64 + n * 16 + fr;
                    const float dot = acc[m][n][q];
                    const float sq = nar + nb[c] - 2.0f * dot;
                    __builtin_nontemporal_store(0.5f * __expf(-sq) + 0.5f * dot,
                                                &out[ro + c]);
                }
            }
        }
        asm volatile("" ::: "memory");
    }
}

// Fallback if workspace is too small: fully naive f32 (correct, slow).
__global__ void naive_kernel(const float* __restrict__ a,
                             const float* __restrict__ b,
                             float* __restrict__ out) {
    const size_t idx = (size_t)blockIdx.x * 256 + threadIdx.x;
    const int i = (int)(idx >> 13);
    const int j = (int)(idx & 8191);
    float dot = 0.f, naa = 0.f, nbb = 0.f;
    for (int k = 0; k < DIM; ++k) {
        const float x = a[(size_t)i * DIM + k];
        const float y = b[(size_t)j * DIM + k];
        dot += x * y; naa += x * x; nbb += y * y;
    }
    const float sq = naa + nbb - 2.0f * dot;
    out[idx] = 0.5f * __expf(-sq) + 0.5f * dot;
}

extern "C" void kernel_launch(void* const* d_in, const int* in_sizes, int n_in,
                              void* d_out, int out_size, void* d_ws, size_t ws_size,
                              hipStream_t stream) {
    const float* a = (const float*)d_in[0];
    const float* b = (const float*)d_in[1];
    // d_in[2] = Wq, d_in[3] = Wk: unused — softmax over a 1x1 score is exactly 1,
    // so attn_sim == a.b and the projections cancel out of the output.
    float* out = (float*)d_out;

    const size_t bf_bytes = (size_t)NROWS * DIM * sizeof(unsigned short); // 4 MB each
    const size_t nrm_bytes = (size_t)NROWS * sizeof(float);               // 32 KB each
    const size_t need = 2 * bf_bytes + 2 * nrm_bytes;

    if (ws_size >= need) {
        unsigned short* aBf = (unsigned short*)d_ws;
        unsigned short* bBf = (unsigned short*)((char*)d_ws + bf_bytes);
        float* na = (float*)((char*)d_ws + 2 * bf_bytes);
        float* nb = (float*)((char*)d_ws + 2 * bf_bytes + nrm_bytes);

        prep_kernel<<<4096, 256, 0, stream>>>(a, b, aBf, bBf, na, nb);
        gemm_kernel<<<GRID_GEMM, 256, 0, stream>>>(aBf, bBf, na, nb, out);
    } else {
        naive_kernel<<<((size_t)NROWS * NROWS) / 256, 256, 0, stream>>>(a, b, out);
    }
}

// Round 3
// 77.172 us; speedup vs baseline: 1.1524x; 1.0539x over previous
//
#include <hip/hip_runtime.h>
#include <stdint.h>

#define DIM 256
#define NR 8192
#define BM 128
#define BN 128
#define BK 64
#define TPB 8           // tiles per block
#define GRID 512        // 64 bx * 8 bb

typedef __bf16 bf16x8 __attribute__((ext_vector_type(8)));
typedef float  f32x16 __attribute__((ext_vector_type(16)));
typedef float  f32x4  __attribute__((ext_vector_type(4)));

#define MEMFENCE asm volatile("" ::: "memory")
#define WAITV(N) asm volatile("s_waitcnt vmcnt(" #N ")" ::: "memory")

__device__ __forceinline__ unsigned short f2bf_rne(float f) {
    unsigned int u = __float_as_uint(f);
    u += 0x7FFFu + ((u >> 16) & 1u);
    return (unsigned short)(u >> 16);
}

// One wave per row: f32 row -> bf16 + ||row||^2. Blocks [0,2048)->a, rest->b.
__global__ void prep_kernel(const float* __restrict__ a,
                            const float* __restrict__ b,
                            unsigned short* __restrict__ aB,
                            unsigned short* __restrict__ bB,
                            float* __restrict__ na,
                            float* __restrict__ nb) {
    const int w = threadIdx.x >> 6;
    const int l = threadIdx.x & 63;
    const int blk = blockIdx.x;
    const float* src; unsigned short* dst; float* nrm; int row;
    if (blk < 2048) { src = a; dst = aB; nrm = na; row = blk * 4 + w; }
    else            { src = b; dst = bB; nrm = nb; row = (blk - 2048) * 4 + w; }
    const float4 v = reinterpret_cast<const float4*>(src + (size_t)row * DIM)[l];
    float ss = v.x * v.x + v.y * v.y + v.z * v.z + v.w * v.w;
#pragma unroll
    for (int off = 32; off > 0; off >>= 1) ss += __shfl_down(ss, off);
    if (l == 0) nrm[row] = ss;
    ushort4 o = make_ushort4(f2bf_rne(v.x), f2bf_rne(v.y), f2bf_rne(v.z), f2bf_rne(v.w));
    reinterpret_cast<ushort4*>(dst + (size_t)row * DIM)[l] = o;
}

// Swizzled staging: LDS granule G=(rp*16+pos) holds global granule
// (r = 2*rp + (c2>>3), c = c2&7) with c2 = pos ^ (rp&15).  Inverse of the
// read mapping byte = ((r>>1)*16 + (((r&1)*8 + c) ^ ((r>>1)&15))) * 16.
#define STAGE(row0_, kt_, buf_)                                                   \
    do {                                                                          \
        _Pragma("unroll")                                                         \
        for (int it_ = 0; it_ < 4; ++it_) {                                       \
            __builtin_amdgcn_global_load_lds(                                     \
                (const __attribute__((address_space(1))) void*)(aB +              \
                    (size_t)((row0_) + rowIt[it_]) * DIM + (kt_) * BK + colIt[it_]), \
                (__attribute__((address_space(3))) void*)&sA[buf_][(w * 4 + it_) * 512], \
                16, 0, 0);                                                        \
        }                                                                         \
        _Pragma("unroll")                                                         \
        for (int it_ = 0; it_ < 4; ++it_) {                                       \
            __builtin_amdgcn_global_load_lds(                                     \
                (const __attribute__((address_space(1))) void*)(bB +              \
                    (size_t)(col0 + rowIt[it_]) * DIM + (kt_) * BK + colIt[it_]), \
                (__attribute__((address_space(3))) void*)&sB[buf_][(w * 4 + it_) * 512], \
                16, 0, 0);                                                        \
        }                                                                         \
    } while (0)

#define COMPUTE(buf_)                                                             \
    do {                                                                          \
        _Pragma("unroll")                                                         \
        for (int ks_ = 0; ks_ < 4; ++ks_) {                                       \
            bf16x8 af[2], bfv[2];                                                 \
            _Pragma("unroll")                                                     \
            for (int mi_ = 0; mi_ < 2; ++mi_)                                     \
                af[mi_] = *(const bf16x8*)((const char*)&sA[buf_][0] +            \
                    baseA[mi_] + ((XA[mi_] ^ (ks_ << 1)) << 4));                  \
            _Pragma("unroll")                                                     \
            for (int ni_ = 0; ni_ < 2; ++ni_)                                     \
                bfv[ni_] = *(const bf16x8*)((const char*)&sB[buf_][0] +           \
                    baseB[ni_] + ((XB[ni_] ^ (ks_ << 1)) << 4));                  \
            _Pragma("unroll")                                                     \
            for (int mi_ = 0; mi_ < 2; ++mi_)                                     \
                _Pragma("unroll")                                                 \
                for (int ni_ = 0; ni_ < 2; ++ni_)                                 \
                    acc[mi_][ni_] = __builtin_amdgcn_mfma_f32_32x32x16_bf16(      \
                        af[mi_], bfv[ni_], acc[mi_][ni_], 0, 0, 0);               \
        }                                                                         \
    } while (0)

__global__ __launch_bounds__(256, 2) void gemm_kernel(
        const unsigned short* __restrict__ aB,
        const unsigned short* __restrict__ bB,
        const float* __restrict__ na,
        const float* __restrict__ nb,
        float* __restrict__ out) {
    __shared__ unsigned short sA[2][8192];
    __shared__ unsigned short sB[2][8192];

    const int t = threadIdx.x;
    const int w = t >> 6, l = t & 63;
    const int wr = w >> 1, wc = w & 1;
    const int hi = l >> 5, lr = l & 31;

    const int bx = (int)blockIdx.x & 63;
    const int bb = (int)blockIdx.x >> 6;
    const int col0 = bx * BN;

    // staging source pre-swizzle (constant per thread)
    int rowIt[4], colIt[4];
#pragma unroll
    for (int it = 0; it < 4; ++it) {
        int G = (w * 4 + it) * 64 + l;
        int rp = G >> 4, pos = G & 15;
        int c2 = pos ^ (rp & 15);
        rowIt[it] = 2 * rp + (c2 >> 3);
        colIt[it] = (c2 & 7) * 8;          // ushort offset
    }
    // fragment read bases (byte offsets within 16KB buffer)
    int baseA[2], XA[2], baseB[2], XB[2];
#pragma unroll
    for (int mi = 0; mi < 2; ++mi) {
        int r = wr * 64 + mi * 32 + lr;
        baseA[mi] = (r >> 1) * 256;
        XA[mi] = (((r & 1) * 8) | hi) ^ ((r >> 1) & 15);
        int rb = wc * 64 + mi * 32 + lr;
        baseB[mi] = (rb >> 1) * 256;
        XB[mi] = (((rb & 1) * 8) | hi) ^ ((rb >> 1) & 15);
    }

    float nbv[2];
#pragma unroll
    for (int ni = 0; ni < 2; ++ni) nbv[ni] = nb[col0 + wc * 64 + ni * 32 + lr];

    float outB[2][16];
    f32x4 nav[2][4];

    // prologue: stage tile0 k0,k1
    {
        const int r0 = bb * BM;
        STAGE(r0, 0, 0);
        STAGE(r0, 1, 1);
    }
    MEMFENCE;

    for (int ti = 0; ti < TPB; ++ti) {
        const int row0 = (bb + ti * 8) * BM;
        f32x16 acc[2][2];
#pragma unroll
        for (int mi = 0; mi < 2; ++mi)
#pragma unroll
            for (int ni = 0; ni < 2; ++ni) acc[mi][ni] = (f32x16)0.0f;

        // ---- P0: compute k0 (buf0) ----
        if (ti == 0) { WAITV(0); } else { WAITV(32); }
        __builtin_amdgcn_s_barrier(); MEMFENCE;
        COMPUTE(0);
        MEMFENCE; __builtin_amdgcn_s_barrier(); MEMFENCE;
        STAGE(row0, 2, 0);
        MEMFENCE;
        if (ti > 0) {  // stB of previous tile (mi=1 rows)
            const int prow = row0 - 1024 + wr * 64 + 32 + 4 * hi;
            const int pcol = col0 + wc * 64 + lr;
#pragma unroll
            for (int ni = 0; ni < 2; ++ni)
#pragma unroll
                for (int tt = 0; tt < 16; ++tt) {
                    int q = tt & 3, p = tt >> 2;
                    __builtin_nontemporal_store(outB[ni][tt],
                        &out[(size_t)(prow + 8 * p + q) * 8192 + pcol + ni * 32]);
                }
        }
        MEMFENCE;

        // ---- P1: compute k1 (buf1) ----
        __builtin_amdgcn_s_barrier(); MEMFENCE;
        COMPUTE(1);
        MEMFENCE; __builtin_amdgcn_s_barrier(); MEMFENCE;
        STAGE(row0, 3, 1);
        MEMFENCE;

        // ---- P2: compute k2 (buf0) ----
        if (ti == 0) { WAITV(8); } else { WAITV(40); }
        __builtin_amdgcn_s_barrier(); MEMFENCE;
        COMPUTE(0);
        MEMFENCE; __builtin_amdgcn_s_barrier(); MEMFENCE;
#pragma unroll
        for (int mi = 0; mi < 2; ++mi)
#pragma unroll
            for (int p = 0; p < 4; ++p)
                nav[mi][p] = *(const f32x4*)&na[row0 + wr * 64 + mi * 32 + 8 * p + 4 * hi];
        MEMFENCE;
        if (ti < TPB - 1) STAGE(row0 + 1024, 0, 0);
        MEMFENCE;

        // ---- P3: compute k3 (buf1) ----
        if (ti == TPB - 1) { WAITV(8); } else { WAITV(16); }
        __builtin_amdgcn_s_barrier(); MEMFENCE;
        COMPUTE(1);
        MEMFENCE; __builtin_amdgcn_s_barrier(); MEMFENCE;
        if (ti < TPB - 1) STAGE(row0 + 1024, 1, 1);
        MEMFENCE;

        // ---- E: epilogue (compiler inserts the counted wait for nav) ----
#pragma unroll
        for (int mi = 0; mi < 2; ++mi)
#pragma unroll
            for (int ni = 0; ni < 2; ++ni)
#pragma unroll
                for (int tt = 0; tt < 16; ++tt) {
                    int q = tt & 3, p = tt >> 2;
                    int row = row0 + wr * 64 + mi * 32 + 8 * p + 4 * hi + q;
                    int col = col0 + wc * 64 + ni * 32 + lr;
                    float dot = acc[mi][ni][tt];
                    float sq = nav[mi][p][q] + nbv[ni] - 2.0f * dot;
                    float v = 0.5f * __expf(-sq) + 0.5f * dot;
                    if (mi == 0)
                        __builtin_nontemporal_store(v, &out[(size_t)row * 8192 + col]);
                    else
                        outB[ni][tt] = v;
                }
        MEMFENCE;
    }

    // stB of the last tile
    {
        const int prow = (bb + 56) * BM + wr * 64 + 32 + 4 * hi;
        const int pcol = col0 + wc * 64 + lr;
#pragma unroll
        for (int ni = 0; ni < 2; ++ni)
#pragma unroll
            for (int tt = 0; tt < 16; ++tt) {
                int q = tt & 3, p = tt >> 2;
                __builtin_nontemporal_store(outB[ni][tt],
                    &out[(size_t)(prow + 8 * p + q) * 8192 + pcol + ni * 32]);
            }
    }
}

// Fallback if workspace is too small: fully naive f32 (correct, slow).
__global__ void naive_kernel(const float* __restrict__ a,
                             const float* __restrict__ b,
                             float* __restrict__ out) {
    const size_t idx = (size_t)blockIdx.x * 256 + threadIdx.x;
    const int i = (int)(idx >> 13);
    const int j = (int)(idx & 8191);
    float dot = 0.f, naa = 0.f, nbb = 0.f;
    for (int k = 0; k < DIM; ++k) {
        const float x = a[(size_t)i * DIM + k];
        const float y = b[(size_t)j * DIM + k];
        dot += x * y; naa += x * x; nbb += y * y;
    }
    const float sq = naa + nbb - 2.0f * dot;
    out[idx] = 0.5f * __expf(-sq) + 0.5f * dot;
}

extern "C" void kernel_launch(void* const* d_in, const int* in_sizes, int n_in,
                              void* d_out, int out_size, void* d_ws, size_t ws_size,
                              hipStream_t stream) {
    const float* a = (const float*)d_in[0];
    const float* b = (const float*)d_in[1];
    // d_in[2]=Wq, d_in[3]=Wk unused: softmax over a 1x1 score == 1 exactly,
    // so attn_sim == a.b and the projections cancel.
    float* out = (float*)d_out;

    const size_t bf_bytes = (size_t)NR * DIM * sizeof(unsigned short);
    const size_t nrm_bytes = (size_t)NR * sizeof(float);
    const size_t need = 2 * bf_bytes + 2 * nrm_bytes;

    if (ws_size >= need) {
        unsigned short* aBf = (unsigned short*)d_ws;
        unsigned short* bBf = (unsigned short*)((char*)d_ws + bf_bytes);
        float* na = (float*)((char*)d_ws + 2 * bf_bytes);
        float* nb = (float*)((char*)d_ws + 2 * bf_bytes + nrm_bytes);

        prep_kernel<<<4096, 256, 0, stream>>>(a, b, aBf, bBf, na, nb);
        gemm_kernel<<<GRID, 256, 0, stream>>>(aBf, bBf, na, nb, out);
    } else {
        naive_kernel<<<((size_t)NR * NR) / 256, 256, 0, stream>>>(a, b, out);
    }
}